// Round 14
// baseline (51.369 us; speedup 1.0000x reference)
//
#include <hip/hip_runtime.h>

#define N 512
#define TOPK 153
#define KP 160
#define D 64
#define NB 32          // batches
#define BN (NB*N)
#define EPSF 1e-8f

typedef __attribute__((ext_vector_type(8))) short bf16x8;   // 8 bf16 (4 VGPR)
typedef __attribute__((ext_vector_type(4))) float f32x4;

// byte-level XOR swizzle: spreads [f][1024B] rows across banks (T2)
#define SWZB(f, byte) ((byte) ^ (((f)&7)<<4))
// u64-word XOR swizzle for bitmask tables: row r word w -> 8 distinct banks
#define GW(r, w) (((r)<<3) + ((w) ^ ((r) & 7)))

static __device__ __forceinline__ unsigned bf16r(float v) {   // f32->bf16 RNE bits
    unsigned u = __float_as_uint(v);
    return (u + 0x7FFFu + ((u >> 16) & 1u)) >> 16;
}

// ---------------- ws layout (bytes) ----------------
// 0x100000: G    u64[N*8]    (32KB)   gated selection bitmask (target-major)
// 0x110000: idxl i32[N*KP]   (320KB)  top-k source ids (arbitrary order)
// 0x160000: rs   f32[N]      1/sqrt(sum_k c_ik^2)  [max_common cancels]
// 0x170000: A_hi bf16[N*N]   (512KB)  dense c^2*rs_i, hi part
// 0x1F0000: A_lo bf16[N*N]   (512KB)  lo part (split precision)
// 0x280000: hT   f32[NB][64][N] (4MB) h transposed per batch

union SMem {
    struct {                     // front blocks (~9.3KB)
        float cr[N];
        float q2[N];
        unsigned long long keys[N];
        unsigned hist[256];
        unsigned wc[8];
        unsigned vstar, above, cnt;
    } f;
};

// blocks 0..511: cosine row + exact top-k SET via radix-select (R9-proven).
// blocks 512..767: h = x @ W via MFMA, zero LDS (R13-proven).
__global__ __launch_bounds__(256)
void k_front9(const float* __restrict__ emb, const float* __restrict__ x,
              const float* __restrict__ W, float* __restrict__ hT,
              int* __restrict__ idxl, unsigned long long* __restrict__ G) {
    int t = threadIdx.x;
    if (blockIdx.x >= 512) {                    // ---- h = x @ W -> hT (MFMA) ----
        int blk = (int)blockIdx.x - 512;        // 0..255
        int r0 = blk * 64;                      // 64 rows per block
        int b = r0 >> 9, jb = r0 & 511;
        int wv = t >> 6, l = t & 63;
        int n = l & 15, ko = l >> 4;
        int f = wv*16 + n;                      // wave = one 16-col N-tile
        f32x4 acc0 = {0,0,0,0}, acc1 = {0,0,0,0}, acc2 = {0,0,0,0}, acc3 = {0,0,0,0};
        #pragma unroll
        for (int ks = 0; ks < 2; ++ks) {
            int kb = ks*32 + ko*8;
            bf16x8 Bh, Bl;
            #pragma unroll
            for (int e = 0; e < 8; ++e) {
                float w = W[(kb+e)*64 + f];
                unsigned hb = bf16r(w);
                Bh[e] = (short)hb;
                Bl[e] = (short)bf16r(w - __uint_as_float(hb<<16));
            }
            #pragma unroll
            for (int mt = 0; mt < 4; ++mt) {
                int row = r0 + mt*16 + n;       // A: lane m = l&15
                const float4* xr = (const float4*)(x + (size_t)row*64 + kb);
                float4 xa = xr[0], xb = xr[1];
                float xv8[8] = {xa.x,xa.y,xa.z,xa.w,xb.x,xb.y,xb.z,xb.w};
                bf16x8 Ah, Al;
                #pragma unroll
                for (int e = 0; e < 8; ++e) {
                    unsigned hb = bf16r(xv8[e]);
                    Ah[e] = (short)hb;
                    Al[e] = (short)bf16r(xv8[e] - __uint_as_float(hb<<16));
                }
                f32x4 a = (mt==0)?acc0:(mt==1)?acc1:(mt==2)?acc2:acc3;
                a = __builtin_amdgcn_mfma_f32_16x16x32_bf16(Ah, Bh, a, 0, 0, 0);
                a = __builtin_amdgcn_mfma_f32_16x16x32_bf16(Ah, Bl, a, 0, 0, 0);
                a = __builtin_amdgcn_mfma_f32_16x16x32_bf16(Al, Bh, a, 0, 0, 0);
                if (mt==0) acc0=a; else if (mt==1) acc1=a; else if (mt==2) acc2=a; else acc3=a;
            }
        }
        #pragma unroll
        for (int r = 0; r < 4; ++r) {
            size_t base = ((size_t)b*64 + f)*512 + jb + ko*4 + r;
            hT[base +  0] = acc0[r];
            hT[base + 16] = acc1[r];
            hT[base + 32] = acc2[r];
            hT[base + 48] = acc3[r];
        }
        return;
    }
    // ---- front: cosine row for node i (R12-proven) ----
    __shared__ SMem sm;
    int i = blockIdx.x;
    float4 ri[16];
    #pragma unroll
    for (int q = 0; q < 16; ++q) ri[q] = ((const float4*)(emb + (size_t)i*64))[q];
    for (int j = t; j < N; j += 256) {          // dot(i,j), |j|^2 in one pass
        const float4* rj = (const float4*)(emb + (size_t)j*64);
        float dot = 0.f, nsq = 0.f;
        #pragma unroll
        for (int q = 0; q < 16; ++q) {
            float4 v = rj[q];
            float4 u = ri[q];
            dot = fmaf(u.x,v.x,fmaf(u.y,v.y,fmaf(u.z,v.z,fmaf(u.w,v.w,dot))));
            nsq = fmaf(v.x,v.x,fmaf(v.y,v.y,fmaf(v.z,v.z,fmaf(v.w,v.w,nsq))));
        }
        sm.f.cr[j] = dot; sm.f.q2[j] = nsq;
    }
    __syncthreads();
    float ni = sqrtf(sm.f.q2[i]);
    for (int j = t; j < N; j += 256) {
        float c = sm.f.cr[j] / (ni*sqrtf(sm.f.q2[j]) + EPSF);
        unsigned u = __float_as_uint(c);
        unsigned s = (u >> 31) ? ~u : (u | 0x80000000u);
        sm.f.keys[j] = (((unsigned long long)s << 9) | (unsigned)(511 - j)) << 23;
    }
    __syncthreads();
    unsigned long long k0 = sm.f.keys[t], k1 = sm.f.keys[t+256];
    // ---- radix-select the 153rd-largest key ----
    unsigned need = TOPK;
    unsigned long long prefix = 0, prefmask = 0;
    for (int dig = 7; dig >= 0; --dig) {
        sm.f.hist[t] = 0;
        __syncthreads();
        int sh = dig*8;
        if ((k0 & prefmask) == prefix) atomicAdd(&sm.f.hist[(unsigned)(k0>>sh)&255], 1u);
        if ((k1 & prefmask) == prefix) atomicAdd(&sm.f.hist[(unsigned)(k1>>sh)&255], 1u);
        __syncthreads();
        if (t < 64) {                           // wave 0: suffix scan over 256 bins
            unsigned c0=sm.f.hist[4*t], c1=sm.f.hist[4*t+1],
                     c2=sm.f.hist[4*t+2], c3=sm.f.hist[4*t+3];
            unsigned T4 = c0+c1+c2+c3;
            unsigned S = T4;
            #pragma unroll
            for (int off = 1; off < 64; off <<= 1) {
                unsigned o = __shfl(S, (t+off < 64) ? t+off : t);
                S += (t+off < 64) ? o : 0;
            }
            unsigned a3 = S - T4;
            unsigned a2 = a3+c3, a1 = a2+c2, a0 = a1+c1;
            if (a3 < need && need <= a3+c3) { sm.f.vstar=4*t+3; sm.f.above=a3; sm.f.cnt=c3; }
            if (a2 < need && need <= a2+c2) { sm.f.vstar=4*t+2; sm.f.above=a2; sm.f.cnt=c2; }
            if (a1 < need && need <= a1+c1) { sm.f.vstar=4*t+1; sm.f.above=a1; sm.f.cnt=c1; }
            if (a0 < need && need <= a0+c0) { sm.f.vstar=4*t;   sm.f.above=a0; sm.f.cnt=c0; }
        }
        __syncthreads();
        unsigned vs = sm.f.vstar, ab = sm.f.above, cv = sm.f.cnt;
        need -= ab;
        prefix   |= ((unsigned long long)vs) << sh;
        prefmask |= 0xFFull << sh;
        if (cv == need) break;
    }
    bool s0 = (k0 >= prefix), s1 = (k1 >= prefix);
    unsigned long long b0 = __ballot(s0), b1 = __ballot(s1);
    int lane = t & 63, w = t >> 6;
    unsigned long long lml = (1ull << lane) - 1;
    if (lane == 0) { sm.f.wc[w] = __popcll(b0); sm.f.wc[4+w] = __popcll(b1); }
    __syncthreads();
    unsigned base0 = 0, base1 = 0;
    #pragma unroll
    for (int m = 0; m < 8; ++m) {
        unsigned c = sm.f.wc[m];
        base0 += (m < w) ? c : 0;
        base1 += (m < 4+w) ? c : 0;
    }
    if (s0) idxl[i*KP + base0 + __popcll(b0 & lml)] = t;
    if (s1) idxl[i*KP + base1 + __popcll(b1 & lml)] = t + 256;
    if (lane == 0) { G[i*8 + w] = b0; G[i*8 + 4 + w] = b1; }
}

// Edge weights via in-LDS bit-matrix transpose (replaces R12's member loop:
// ~460 serial LDS broadcasts/wave -> 6-step shfl_xor transpose, ~580 LDS ops
// total). gs/gt stored with GW word-XOR swizzle -> 8-bank spread on tile
// reads/writes and per-thread row reads (naive layout is 2-bank/32-way).
// c(i,j) = popcount(nb_i & nb_j), nb_j = gs_j | gt_j | e_j -- exact.
__global__ __launch_bounds__(256)
void k_edge5(const unsigned long long* __restrict__ G,
             const int* __restrict__ idxl, float* __restrict__ rs,
             unsigned short* __restrict__ A_hi, unsigned short* __restrict__ A_lo) {
    __shared__ unsigned long long gs[N*8];       // 32KB: G, swizzled
    __shared__ unsigned long long gt[N*8];       // 32KB: G^T, swizzled
    __shared__ unsigned long long nb8[8];
    __shared__ float red[4];
    __shared__ float rsb;
    int i = blockIdx.x, t = threadIdx.x;
    for (int e = t; e < 4096; e += 256) {        // stage G (swizzled words)
        int r = e >> 3, w = e & 7;
        gs[GW(r, w)] = G[e];
    }
    ((unsigned*)(A_hi + (size_t)i*512))[t] = 0;  // zero A row (256 u32 = 512 bf16)
    ((unsigned*)(A_lo + (size_t)i*512))[t] = 0;
    __syncthreads();
    // in-LDS 512x512 bit transpose: 64 tiles of 64x64, 16 tiles per wave.
    // Standard 6-step: swap off-diagonal k-blocks via shfl_xor + mask.
    int lane = t & 63, wv = t >> 6;
    for (int tile = wv; tile < 64; tile += 4) {
        int R = tile >> 3, C = tile & 7;
        unsigned long long xx = gs[GW(R*64 + lane, C)];
        #pragma unroll
        for (int s = 0; s < 6; ++s) {
            const int k = 32 >> s;
            const unsigned long long mask =
                (s==0) ? 0x00000000FFFFFFFFull : (s==1) ? 0x0000FFFF0000FFFFull :
                (s==2) ? 0x00FF00FF00FF00FFull : (s==3) ? 0x0F0F0F0F0F0F0F0Full :
                (s==4) ? 0x3333333333333333ull : 0x5555555555555555ull;
            unsigned long long p = __shfl_xor(xx, k, 64);
            xx = (lane & k) ? ((xx & ~mask) | ((p >> k) & mask))
                            : ((xx & mask) | ((p & mask) << k));
        }
        gt[GW(C*64 + lane, R)] = xx;             // lane l = column 64C+l of tile
    }
    __syncthreads();
    if (t < 8) {                                 // nb_i, broadcast
        unsigned long long v = gs[GW(i, t)] | gt[GW(i, t)];
        if ((i >> 6) == t) v |= 1ull << (i & 63);
        nb8[t] = v;
    }
    __syncthreads();
    float c2 = 0.f; int j = 0;
    if (t < TOPK) {
        j = idxl[i*KP + t];
        int jw = j >> 6; unsigned long long jb = 1ull << (j & 63);
        int c = 0;
        #pragma unroll
        for (int w = 0; w < 8; ++w) {
            unsigned long long nj = gs[GW(j, w)] | gt[GW(j, w)];
            if (w == jw) nj |= jb;               // self loop
            c += __popcll(nb8[w] & nj);
        }
        c2 = (float)(c*c);                       // edge always has c>=2
    }
    float s = c2;
    #pragma unroll
    for (int o = 32; o > 0; o >>= 1) s += __shfl_down(s, o, 64);
    if ((t & 63) == 0) red[t>>6] = s;
    __syncthreads();
    if (t == 0) {
        float deg = red[0]+red[1]+red[2]+red[3];
        float r = (float)(1.0/sqrt((double)deg));
        rsb = r; rs[i] = r;
    }
    __syncthreads();
    if (t < TOPK) {
        float wv2 = c2 * rsb;
        unsigned hb = bf16r(wv2);
        float fhi = __uint_as_float(hb << 16);
        unsigned lb = bf16r(wv2 - fhi);
        A_hi[(size_t)i*512 + j] = (unsigned short)hb;
        A_lo[(size_t)i*512 + j] = (unsigned short)lb;
    }
}

// Dense MFMA aggregate: out_b = A @ (rs .* h_b) + bias, bf16-split 3-pass.
__global__ __launch_bounds__(512)
void k_agg4(const float* __restrict__ hT, const float* __restrict__ rs,
            const unsigned short* __restrict__ Ahg, const unsigned short* __restrict__ Alg,
            const float* __restrict__ bias, float* __restrict__ out) {
    __shared__ char glds[131072];        // [0,64K): g_hi   [64K,128K): g_lo
    int chunk = blockIdx.x, b = blockIdx.y, t = threadIdx.x;
    const float4* hb = (const float4*)(hT + (size_t)b*64*512);
    for (int e = t; e < 8192; e += 512) {
        int f = e >> 7;
        int j0 = (e & 127) << 2;
        float4 v = hb[e];
        float4 rv = *(const float4*)&rs[j0];
        float v0 = v.x*rv.x, v1 = v.y*rv.y, v2 = v.z*rv.z, v3 = v.w*rv.w;
        unsigned h0 = bf16r(v0), h1 = bf16r(v1), h2 = bf16r(v2), h3 = bf16r(v3);
        unsigned l0 = bf16r(v0 - __uint_as_float(h0<<16));
        unsigned l1 = bf16r(v1 - __uint_as_float(h1<<16));
        unsigned l2 = bf16r(v2 - __uint_as_float(h2<<16));
        unsigned l3 = bf16r(v3 - __uint_as_float(h3<<16));
        unsigned long long hp = (unsigned long long)h0 | ((unsigned long long)h1<<16)
                              | ((unsigned long long)h2<<32) | ((unsigned long long)h3<<48);
        unsigned long long lp = (unsigned long long)l0 | ((unsigned long long)l1<<16)
                              | ((unsigned long long)l2<<32) | ((unsigned long long)l3<<48);
        int byte = f*1024 + j0*2;
        *(unsigned long long*)(glds + SWZB(f, byte)) = hp;
        *(unsigned long long*)(glds + 65536 + SWZB(f, byte)) = lp;
    }
    __syncthreads();
    int wid = t >> 6, l = t & 63;
    int wr = wid >> 1, wc = wid & 1;
    int m = l & 15, kg = (l >> 4) * 8;
    int trow = chunk*64 + wr*16 + m;
    const unsigned short* arh = Ahg + (size_t)trow*512 + kg;
    const unsigned short* arl = Alg + (size_t)trow*512 + kg;
    int f0 = wc*32 + m, f1 = f0 + 16;
    f32x4 acc0 = {0.f,0.f,0.f,0.f}, acc1 = {0.f,0.f,0.f,0.f};
    #pragma unroll 4
    for (int k0 = 0; k0 < 512; k0 += 32) {
        bf16x8 Ah = *(const bf16x8*)(arh + k0);
        bf16x8 Al = *(const bf16x8*)(arl + k0);
        int kb = (k0 + kg) * 2;
        bf16x8 B0h = *(const bf16x8*)(glds + SWZB(f0, f0*1024 + kb));
        bf16x8 B0l = *(const bf16x8*)(glds + 65536 + SWZB(f0, f0*1024 + kb));
        bf16x8 B1h = *(const bf16x8*)(glds + SWZB(f1, f1*1024 + kb));
        bf16x8 B1l = *(const bf16x8*)(glds + 65536 + SWZB(f1, f1*1024 + kb));
        acc0 = __builtin_amdgcn_mfma_f32_16x16x32_bf16(Ah, B0h, acc0, 0, 0, 0);
        acc0 = __builtin_amdgcn_mfma_f32_16x16x32_bf16(Ah, B0l, acc0, 0, 0, 0);
        acc0 = __builtin_amdgcn_mfma_f32_16x16x32_bf16(Al, B0h, acc0, 0, 0, 0);
        acc1 = __builtin_amdgcn_mfma_f32_16x16x32_bf16(Ah, B1h, acc1, 0, 0, 0);
        acc1 = __builtin_amdgcn_mfma_f32_16x16x32_bf16(Ah, B1l, acc1, 0, 0, 0);
        acc1 = __builtin_amdgcn_mfma_f32_16x16x32_bf16(Al, B1h, acc1, 0, 0, 0);
    }
    float bb0 = bias[f0], bb1 = bias[f1];
    size_t ob = (size_t)(b*512 + chunk*64 + wr*16) * 64;
    #pragma unroll
    for (int r = 0; r < 4; ++r) {
        int row = (l >> 4) * 4 + r;
        out[ob + (size_t)row*64 + f0] = acc0[r] + bb0;
        out[ob + (size_t)row*64 + f1] = acc1[r] + bb1;
    }
}

extern "C" void kernel_launch(void* const* d_in, const int* in_sizes, int n_in,
                              void* d_out, int out_size, void* d_ws, size_t ws_size,
                              hipStream_t stream) {
    const float* x    = (const float*)d_in[0];   // [32,512,64]
    const float* W    = (const float*)d_in[1];   // [64,64]
    const float* bias = (const float*)d_in[2];   // [64]
    const float* emb  = (const float*)d_in[3];   // [512,64]
    float* out = (float*)d_out;

    char* ws = (char*)d_ws;
    unsigned long long* G = (unsigned long long*)(ws + 0x100000);
    int*   idxl = (int*)(ws + 0x110000);
    float* rs   = (float*)(ws + 0x160000);
    unsigned short* A_hi = (unsigned short*)(ws + 0x170000);
    unsigned short* A_lo = (unsigned short*)(ws + 0x1F0000);
    float* hT   = (float*)(ws + 0x280000);

    k_front9<<<512 + 256, 256, 0, stream>>>(emb, x, W, hT, idxl, G);
    k_edge5<<<N, 256, 0, stream>>>(G, idxl, rs, A_hi, A_lo);
    k_agg4<<<dim3(8, NB), 512, 0, stream>>>(hT, rs, A_hi, A_lo, bias, out);
}

// Round 15
// 41.964 us; speedup vs baseline: 1.2241x; 1.2241x over previous
//
#include <hip/hip_runtime.h>

#define N 512
#define TOPK 153
#define KP 160
#define D 64
#define NB 32          // batches
#define BN (NB*N)
#define EPSF 1e-8f

typedef __attribute__((ext_vector_type(8))) short bf16x8;   // 8 bf16 (4 VGPR)
typedef __attribute__((ext_vector_type(4))) float f32x4;

// byte-level XOR swizzle: spreads [f][1024B] rows across banks (T2)
#define SWZB(f, byte) ((byte) ^ (((f)&7)<<4))

static __device__ __forceinline__ unsigned bf16r(float v) {   // f32->bf16 RNE bits
    unsigned u = __float_as_uint(v);
    return (u + 0x7FFFu + ((u >> 16) & 1u)) >> 16;
}

// ---------------- ws layout (bytes) ----------------
// 0x100000: G    u64[N*8]    (32KB)   gated selection bitmask (target-major)
// 0x108000: GT   u64[N*8]    (32KB)   G transposed (built by k_trans, no atomics)
// 0x110000: idxl i32[N*KP]   (320KB)  top-k source ids (arbitrary order)
// 0x160000: rs   f32[N]      1/sqrt(sum_k c_ik^2)  [max_common cancels]
// 0x170000: A_hi bf16[N*N]   (512KB)  dense c^2*rs_i, hi part
// 0x1F0000: A_lo bf16[N*N]   (512KB)  lo part (split precision)
// 0x280000: hT   f32[NB][64][N] (4MB) h transposed per batch

union SMem {
    struct {                     // front blocks (~9.3KB)
        float cr[N];
        float q2[N];
        unsigned long long keys[N];
        unsigned hist[256];
        unsigned wc[8];
        unsigned vstar, above, cnt;
    } f;
};

// blocks 0..511: cosine row + exact top-k SET via radix-select (R9-proven).
// blocks 512..767: h = x @ W via MFMA, zero LDS (R13-proven).
__global__ __launch_bounds__(256)
void k_front9(const float* __restrict__ emb, const float* __restrict__ x,
              const float* __restrict__ W, float* __restrict__ hT,
              int* __restrict__ idxl, unsigned long long* __restrict__ G) {
    int t = threadIdx.x;
    if (blockIdx.x >= 512) {                    // ---- h = x @ W -> hT (MFMA) ----
        int blk = (int)blockIdx.x - 512;        // 0..255
        int r0 = blk * 64;                      // 64 rows per block
        int b = r0 >> 9, jb = r0 & 511;
        int wv = t >> 6, l = t & 63;
        int n = l & 15, ko = l >> 4;
        int f = wv*16 + n;                      // wave = one 16-col N-tile
        f32x4 acc0 = {0,0,0,0}, acc1 = {0,0,0,0}, acc2 = {0,0,0,0}, acc3 = {0,0,0,0};
        #pragma unroll
        for (int ks = 0; ks < 2; ++ks) {
            int kb = ks*32 + ko*8;
            bf16x8 Bh, Bl;
            #pragma unroll
            for (int e = 0; e < 8; ++e) {
                float w = W[(kb+e)*64 + f];
                unsigned hb = bf16r(w);
                Bh[e] = (short)hb;
                Bl[e] = (short)bf16r(w - __uint_as_float(hb<<16));
            }
            #pragma unroll
            for (int mt = 0; mt < 4; ++mt) {
                int row = r0 + mt*16 + n;       // A: lane m = l&15
                const float4* xr = (const float4*)(x + (size_t)row*64 + kb);
                float4 xa = xr[0], xb = xr[1];
                float xv8[8] = {xa.x,xa.y,xa.z,xa.w,xb.x,xb.y,xb.z,xb.w};
                bf16x8 Ah, Al;
                #pragma unroll
                for (int e = 0; e < 8; ++e) {
                    unsigned hb = bf16r(xv8[e]);
                    Ah[e] = (short)hb;
                    Al[e] = (short)bf16r(xv8[e] - __uint_as_float(hb<<16));
                }
                f32x4 a = (mt==0)?acc0:(mt==1)?acc1:(mt==2)?acc2:acc3;
                a = __builtin_amdgcn_mfma_f32_16x16x32_bf16(Ah, Bh, a, 0, 0, 0);
                a = __builtin_amdgcn_mfma_f32_16x16x32_bf16(Ah, Bl, a, 0, 0, 0);
                a = __builtin_amdgcn_mfma_f32_16x16x32_bf16(Al, Bh, a, 0, 0, 0);
                if (mt==0) acc0=a; else if (mt==1) acc1=a; else if (mt==2) acc2=a; else acc3=a;
            }
        }
        #pragma unroll
        for (int r = 0; r < 4; ++r) {
            size_t base = ((size_t)b*64 + f)*512 + jb + ko*4 + r;
            hT[base +  0] = acc0[r];
            hT[base + 16] = acc1[r];
            hT[base + 32] = acc2[r];
            hT[base + 48] = acc3[r];
        }
        return;
    }
    // ---- front: cosine row for node i (R12-proven) ----
    __shared__ SMem sm;
    int i = blockIdx.x;
    float4 ri[16];
    #pragma unroll
    for (int q = 0; q < 16; ++q) ri[q] = ((const float4*)(emb + (size_t)i*64))[q];
    for (int j = t; j < N; j += 256) {          // dot(i,j), |j|^2 in one pass
        const float4* rj = (const float4*)(emb + (size_t)j*64);
        float dot = 0.f, nsq = 0.f;
        #pragma unroll
        for (int q = 0; q < 16; ++q) {
            float4 v = rj[q];
            float4 u = ri[q];
            dot = fmaf(u.x,v.x,fmaf(u.y,v.y,fmaf(u.z,v.z,fmaf(u.w,v.w,dot))));
            nsq = fmaf(v.x,v.x,fmaf(v.y,v.y,fmaf(v.z,v.z,fmaf(v.w,v.w,nsq))));
        }
        sm.f.cr[j] = dot; sm.f.q2[j] = nsq;
    }
    __syncthreads();
    float ni = sqrtf(sm.f.q2[i]);
    for (int j = t; j < N; j += 256) {
        float c = sm.f.cr[j] / (ni*sqrtf(sm.f.q2[j]) + EPSF);
        unsigned u = __float_as_uint(c);
        unsigned s = (u >> 31) ? ~u : (u | 0x80000000u);
        sm.f.keys[j] = (((unsigned long long)s << 9) | (unsigned)(511 - j)) << 23;
    }
    __syncthreads();
    unsigned long long k0 = sm.f.keys[t], k1 = sm.f.keys[t+256];
    // ---- radix-select the 153rd-largest key ----
    unsigned need = TOPK;
    unsigned long long prefix = 0, prefmask = 0;
    for (int dig = 7; dig >= 0; --dig) {
        sm.f.hist[t] = 0;
        __syncthreads();
        int sh = dig*8;
        if ((k0 & prefmask) == prefix) atomicAdd(&sm.f.hist[(unsigned)(k0>>sh)&255], 1u);
        if ((k1 & prefmask) == prefix) atomicAdd(&sm.f.hist[(unsigned)(k1>>sh)&255], 1u);
        __syncthreads();
        if (t < 64) {                           // wave 0: suffix scan over 256 bins
            unsigned c0=sm.f.hist[4*t], c1=sm.f.hist[4*t+1],
                     c2=sm.f.hist[4*t+2], c3=sm.f.hist[4*t+3];
            unsigned T4 = c0+c1+c2+c3;
            unsigned S = T4;
            #pragma unroll
            for (int off = 1; off < 64; off <<= 1) {
                unsigned o = __shfl(S, (t+off < 64) ? t+off : t);
                S += (t+off < 64) ? o : 0;
            }
            unsigned a3 = S - T4;
            unsigned a2 = a3+c3, a1 = a2+c2, a0 = a1+c1;
            if (a3 < need && need <= a3+c3) { sm.f.vstar=4*t+3; sm.f.above=a3; sm.f.cnt=c3; }
            if (a2 < need && need <= a2+c2) { sm.f.vstar=4*t+2; sm.f.above=a2; sm.f.cnt=c2; }
            if (a1 < need && need <= a1+c1) { sm.f.vstar=4*t+1; sm.f.above=a1; sm.f.cnt=c1; }
            if (a0 < need && need <= a0+c0) { sm.f.vstar=4*t;   sm.f.above=a0; sm.f.cnt=c0; }
        }
        __syncthreads();
        unsigned vs = sm.f.vstar, ab = sm.f.above, cv = sm.f.cnt;
        need -= ab;
        prefix   |= ((unsigned long long)vs) << sh;
        prefmask |= 0xFFull << sh;
        if (cv == need) break;
    }
    bool s0 = (k0 >= prefix), s1 = (k1 >= prefix);
    unsigned long long b0 = __ballot(s0), b1 = __ballot(s1);
    int lane = t & 63, w = t >> 6;
    unsigned long long lml = (1ull << lane) - 1;
    if (lane == 0) { sm.f.wc[w] = __popcll(b0); sm.f.wc[4+w] = __popcll(b1); }
    __syncthreads();
    unsigned base0 = 0, base1 = 0;
    #pragma unroll
    for (int m = 0; m < 8; ++m) {
        unsigned c = sm.f.wc[m];
        base0 += (m < w) ? c : 0;
        base1 += (m < 4+w) ? c : 0;
    }
    if (s0) idxl[i*KP + base0 + __popcll(b0 & lml)] = t;
    if (s1) idxl[i*KP + base1 + __popcll(b1 & lml)] = t + 256;
    if (lane == 0) { G[i*8 + w] = b0; G[i*8 + 4 + w] = b1; }
}

// One-shot 512x512 bit transpose: 64 tiles of 64x64 bits, one tile per wave
// (16 blocks x 4 waves). 6-step shfl_xor algorithm (R14-verified correct).
// Full-word writes -> no zeroing, no atomics. Tiny: 4096 u64 total.
__global__ __launch_bounds__(256)
void k_trans(const unsigned long long* __restrict__ G,
             unsigned long long* __restrict__ GT) {
    int t = threadIdx.x;
    int lane = t & 63, wv = t >> 6;
    int tile = blockIdx.x*4 + wv;               // 0..63
    int R = tile >> 3, C = tile & 7;
    unsigned long long xx = G[(R*64 + lane)*8 + C];
    #pragma unroll
    for (int s = 0; s < 6; ++s) {
        const int k = 32 >> s;
        const unsigned long long mask =
            (s==0) ? 0x00000000FFFFFFFFull : (s==1) ? 0x0000FFFF0000FFFFull :
            (s==2) ? 0x00FF00FF00FF00FFull : (s==3) ? 0x0F0F0F0F0F0F0F0Full :
            (s==4) ? 0x3333333333333333ull : 0x5555555555555555ull;
        unsigned long long p = __shfl_xor(xx, k, 64);
        xx = (lane & k) ? ((xx & ~mask) | ((p >> k) & mask))
                        : ((xx & mask) | ((p & mask) << k));
    }
    GT[(C*64 + lane)*8 + R] = xx;               // lane l = column 64C+l of tile
}

// Edge weights, R10-proven inner loop: nb = G|GT|self read straight from
// global (both 32KB, L2-hot); c = popcount(nb_i & nb_j) per edge; no member
// loop, no in-block transpose. Writes dense A row (c^2*rs_i bf16 hi/lo) + rs.
__global__ __launch_bounds__(256)
void k_edge6(const unsigned long long* __restrict__ G,
             const unsigned long long* __restrict__ GT,
             const int* __restrict__ idxl, float* __restrict__ rs,
             unsigned short* __restrict__ A_hi, unsigned short* __restrict__ A_lo) {
    __shared__ unsigned long long ni[8];
    __shared__ float red[4];
    __shared__ float rsb;
    int i = blockIdx.x, k = threadIdx.x;
    if (k < 8) {
        unsigned long long v = G[i*8+k] | GT[i*8+k];
        if ((i>>6) == k) v |= 1ull << (i&63);    // self loop
        ni[k] = v;
    }
    ((unsigned*)(A_hi + (size_t)i*512))[k] = 0;  // zero row (256 u32 = 512 bf16)
    ((unsigned*)(A_lo + (size_t)i*512))[k] = 0;
    __syncthreads();
    float c2 = 0.f; int j = 0;
    if (k < TOPK) {
        j = idxl[i*KP+k];
        int jw = j >> 6; unsigned long long jb = 1ull << (j&63);
        int c = 0;
        #pragma unroll
        for (int w = 0; w < 8; ++w) {
            unsigned long long nj = G[j*8+w] | GT[j*8+w];
            if (w == jw) nj |= jb;               // self loop (compile-time w)
            c += __popcll(ni[w] & nj);
        }
        c2 = (float)(c*c);                       // edge always has c>=2
    }
    float s = c2;
    #pragma unroll
    for (int o = 32; o > 0; o >>= 1) s += __shfl_down(s, o, 64);
    if ((k & 63) == 0) red[k>>6] = s;
    __syncthreads();
    if (k == 0) {
        float deg = red[0]+red[1]+red[2]+red[3]; // > 0 always
        float r = (float)(1.0/sqrt((double)deg));
        rsb = r; rs[i] = r;
    }
    __syncthreads();
    if (k < TOPK) {
        float wv = c2 * rsb;
        unsigned hb = bf16r(wv);
        float fhi = __uint_as_float(hb << 16);
        unsigned lb = bf16r(wv - fhi);
        A_hi[(size_t)i*512 + j] = (unsigned short)hb;
        A_lo[(size_t)i*512 + j] = (unsigned short)lb;
    }
}

// Dense MFMA aggregate: out_b = A @ (rs .* h_b) + bias, bf16-split 3-pass.
__global__ __launch_bounds__(512)
void k_agg4(const float* __restrict__ hT, const float* __restrict__ rs,
            const unsigned short* __restrict__ Ahg, const unsigned short* __restrict__ Alg,
            const float* __restrict__ bias, float* __restrict__ out) {
    __shared__ char glds[131072];        // [0,64K): g_hi   [64K,128K): g_lo
    int chunk = blockIdx.x, b = blockIdx.y, t = threadIdx.x;
    const float4* hb = (const float4*)(hT + (size_t)b*64*512);
    for (int e = t; e < 8192; e += 512) {
        int f = e >> 7;
        int j0 = (e & 127) << 2;
        float4 v = hb[e];
        float4 rv = *(const float4*)&rs[j0];
        float v0 = v.x*rv.x, v1 = v.y*rv.y, v2 = v.z*rv.z, v3 = v.w*rv.w;
        unsigned h0 = bf16r(v0), h1 = bf16r(v1), h2 = bf16r(v2), h3 = bf16r(v3);
        unsigned l0 = bf16r(v0 - __uint_as_float(h0<<16));
        unsigned l1 = bf16r(v1 - __uint_as_float(h1<<16));
        unsigned l2 = bf16r(v2 - __uint_as_float(h2<<16));
        unsigned l3 = bf16r(v3 - __uint_as_float(h3<<16));
        unsigned long long hp = (unsigned long long)h0 | ((unsigned long long)h1<<16)
                              | ((unsigned long long)h2<<32) | ((unsigned long long)h3<<48);
        unsigned long long lp = (unsigned long long)l0 | ((unsigned long long)l1<<16)
                              | ((unsigned long long)l2<<32) | ((unsigned long long)l3<<48);
        int byte = f*1024 + j0*2;
        *(unsigned long long*)(glds + SWZB(f, byte)) = hp;
        *(unsigned long long*)(glds + 65536 + SWZB(f, byte)) = lp;
    }
    __syncthreads();
    int wid = t >> 6, l = t & 63;
    int wr = wid >> 1, wc = wid & 1;
    int m = l & 15, kg = (l >> 4) * 8;
    int trow = chunk*64 + wr*16 + m;
    const unsigned short* arh = Ahg + (size_t)trow*512 + kg;
    const unsigned short* arl = Alg + (size_t)trow*512 + kg;
    int f0 = wc*32 + m, f1 = f0 + 16;
    f32x4 acc0 = {0.f,0.f,0.f,0.f}, acc1 = {0.f,0.f,0.f,0.f};
    #pragma unroll 4
    for (int k0 = 0; k0 < 512; k0 += 32) {
        bf16x8 Ah = *(const bf16x8*)(arh + k0);
        bf16x8 Al = *(const bf16x8*)(arl + k0);
        int kb = (k0 + kg) * 2;
        bf16x8 B0h = *(const bf16x8*)(glds + SWZB(f0, f0*1024 + kb));
        bf16x8 B0l = *(const bf16x8*)(glds + 65536 + SWZB(f0, f0*1024 + kb));
        bf16x8 B1h = *(const bf16x8*)(glds + SWZB(f1, f1*1024 + kb));
        bf16x8 B1l = *(const bf16x8*)(glds + 65536 + SWZB(f1, f1*1024 + kb));
        acc0 = __builtin_amdgcn_mfma_f32_16x16x32_bf16(Ah, B0h, acc0, 0, 0, 0);
        acc0 = __builtin_amdgcn_mfma_f32_16x16x32_bf16(Ah, B0l, acc0, 0, 0, 0);
        acc0 = __builtin_amdgcn_mfma_f32_16x16x32_bf16(Al, B0h, acc0, 0, 0, 0);
        acc1 = __builtin_amdgcn_mfma_f32_16x16x32_bf16(Ah, B1h, acc1, 0, 0, 0);
        acc1 = __builtin_amdgcn_mfma_f32_16x16x32_bf16(Ah, B1l, acc1, 0, 0, 0);
        acc1 = __builtin_amdgcn_mfma_f32_16x16x32_bf16(Al, B1h, acc1, 0, 0, 0);
    }
    float bb0 = bias[f0], bb1 = bias[f1];
    size_t ob = (size_t)(b*512 + chunk*64 + wr*16) * 64;
    #pragma unroll
    for (int r = 0; r < 4; ++r) {
        int row = (l >> 4) * 4 + r;
        out[ob + (size_t)row*64 + f0] = acc0[r] + bb0;
        out[ob + (size_t)row*64 + f1] = acc1[r] + bb1;
    }
}

extern "C" void kernel_launch(void* const* d_in, const int* in_sizes, int n_in,
                              void* d_out, int out_size, void* d_ws, size_t ws_size,
                              hipStream_t stream) {
    const float* x    = (const float*)d_in[0];   // [32,512,64]
    const float* W    = (const float*)d_in[1];   // [64,64]
    const float* bias = (const float*)d_in[2];   // [64]
    const float* emb  = (const float*)d_in[3];   // [512,64]
    float* out = (float*)d_out;

    char* ws = (char*)d_ws;
    unsigned long long* G  = (unsigned long long*)(ws + 0x100000);
    unsigned long long* GT = (unsigned long long*)(ws + 0x108000);
    int*   idxl = (int*)(ws + 0x110000);
    float* rs   = (float*)(ws + 0x160000);
    unsigned short* A_hi = (unsigned short*)(ws + 0x170000);
    unsigned short* A_lo = (unsigned short*)(ws + 0x1F0000);
    float* hT   = (float*)(ws + 0x280000);

    k_front9<<<512 + 256, 256, 0, stream>>>(emb, x, W, hT, idxl, G);
    k_trans<<<16, 256, 0, stream>>>(G, GT);
    k_edge6<<<N, 256, 0, stream>>>(G, GT, idxl, rs, A_hi, A_lo);
    k_agg4<<<dim3(8, NB), 512, 0, stream>>>(hT, rs, A_hi, A_lo, bias, out);
}